// Round 1
// baseline (770.041 us; speedup 1.0000x reference)
//
#include <hip/hip_runtime.h>
#include <hip/hip_bf16.h>
#include <math.h>

// Problem: B=1, S=8192, H=1024.
//   q = tanh(enc @ w1^T); k = enc @ w2^T; scores = q @ k^T  [S,S]
//   attn = softmax over rows (axis i) per column j
//   context = col_sum(attn) * enc = enc  (col_sum == 1 exactly)
// Outputs concat: d_out[0:8388608] = context f32, d_out[8388608:] = attn f32.

typedef _Float16 half_t;
typedef _Float16 half8 __attribute__((ext_vector_type(8)));
typedef _Float16 half4 __attribute__((ext_vector_type(4)));
typedef float f32x4 __attribute__((ext_vector_type(4)));

#define S_DIM 8192
#define H_DIM 1024

__device__ __forceinline__ void gload16(const void* g, void* l) {
  __builtin_amdgcn_global_load_lds(
      (const __attribute__((address_space(1))) void*)g,
      (__attribute__((address_space(3))) void*)l, 16, 0, 0);
}

// ---------------- f32 -> fp16 convert (n4 float4-groups, grid covers exactly) --
__global__ void __launch_bounds__(256) k_cvt(const float* __restrict__ src,
                                             half_t* __restrict__ dst) {
  long g = (long)blockIdx.x * 256 + threadIdx.x;
  f32x4 x = ((const f32x4*)src)[g];
  half4 h;
#pragma unroll
  for (int e = 0; e < 4; ++e) h[e] = (half_t)x[e];
  ((half4*)dst)[g] = h;
}

// ---------------- GEMM_BT mainloop (shared by both GEMMs) ---------------------
// C[128x128] per block, 4 waves each 64x64, K=1024, BK=64.
// LDS layout: unit-major [u(0..7)][m(0..127)][8 halfs]; staged via global_load_lds
// (lane-linear contiguous => wave-uniform base + lane*16, as HW requires).
#define GEMM_MAINLOOP(APTR, BPTR)                                              \
  __shared__ half_t As[8192];                                                  \
  __shared__ half_t Bs[8192];                                                  \
  const int tid = threadIdx.x;                                                 \
  const int lane = tid & 63;                                                   \
  const int quad = lane >> 4;                                                  \
  const int l15 = lane & 15;                                                   \
  const int wave = tid >> 6;                                                   \
  const int wm = wave & 1;                                                     \
  const int wn = wave >> 1;                                                    \
  const int bm = blockIdx.y;                                                   \
  const int bn = blockIdx.x;                                                   \
  int aoff[4], boff[4], loff[4];                                               \
  _Pragma("unroll") for (int t = 0; t < 4; ++t) {                              \
    int f8 = t * 256 + tid;                                                    \
    int u = f8 >> 7;                                                           \
    int m = f8 & 127;                                                          \
    aoff[t] = (bm * 128 + m) * H_DIM + u * 8;                                  \
    boff[t] = (bn * 128 + m) * H_DIM + u * 8;                                  \
    loff[t] = f8 * 8;                                                          \
  }                                                                            \
  f32x4 acc[4][4];                                                             \
  _Pragma("unroll") for (int r = 0; r < 4; ++r)                                \
      _Pragma("unroll") for (int c = 0; c < 4; ++c)                            \
          acc[r][c] = (f32x4){0.f, 0.f, 0.f, 0.f};                             \
  for (int k0 = 0; k0 < H_DIM; k0 += 64) {                                     \
    _Pragma("unroll") for (int t = 0; t < 4; ++t)                              \
        gload16(APTR + aoff[t] + k0, &As[loff[t]]);                            \
    _Pragma("unroll") for (int t = 0; t < 4; ++t)                              \
        gload16(BPTR + boff[t] + k0, &Bs[loff[t]]);                            \
    __syncthreads();                                                           \
    _Pragma("unroll") for (int ki = 0; ki < 2; ++ki) {                         \
      const int u = ki * 4 + quad;                                             \
      half8 af[4], bf[4];                                                      \
      _Pragma("unroll") for (int r = 0; r < 4; ++r)                            \
          af[r] = *(const half8*)&As[(u * 128 + wm * 64 + r * 16 + l15) * 8];  \
      _Pragma("unroll") for (int c = 0; c < 4; ++c)                            \
          bf[c] = *(const half8*)&Bs[(u * 128 + wn * 64 + c * 16 + l15) * 8];  \
      _Pragma("unroll") for (int r = 0; r < 4; ++r)                            \
          _Pragma("unroll") for (int c = 0; c < 4; ++c)                        \
              acc[r][c] = __builtin_amdgcn_mfma_f32_16x16x32_f16(              \
                  af[r], bf[c], acc[r][c], 0, 0, 0);                           \
    }                                                                          \
    __syncthreads();                                                           \
  }

// K1: X[8192,2048] = enc_h @ w_h^T; cols<1024 -> tanh -> Qh, else -> Kh (fp16)
__global__ void __launch_bounds__(256) k_gemm_qk(const half_t* __restrict__ A,
                                                 const half_t* __restrict__ B,
                                                 half_t* __restrict__ Qh,
                                                 half_t* __restrict__ Kh) {
  GEMM_MAINLOOP(A, B)
  const int colbase = bn * 128 + wn * 64;
  const int rowb = bm * 128 + wm * 64;
#pragma unroll
  for (int r = 0; r < 4; ++r) {
#pragma unroll
    for (int c = 0; c < 4; ++c) {
      int col = colbase + c * 16 + l15;
      int row = rowb + r * 16 + quad * 4;
#pragma unroll
      for (int v = 0; v < 4; ++v) {
        float x = acc[r][c][v];
        if (col < 1024) {
          Qh[(long)(row + v) * 1024 + col] = (half_t)tanhf(x);
        } else {
          Kh[(long)(row + v) * 1024 + (col - 1024)] = (half_t)x;
        }
      }
    }
  }
}

// K2: scores[8192,8192] f32 = Qh @ Kh^T
__global__ void __launch_bounds__(256) k_gemm_scores(const half_t* __restrict__ A,
                                                     const half_t* __restrict__ B,
                                                     float* __restrict__ out) {
  GEMM_MAINLOOP(A, B)
  const int colbase = bn * 128 + wn * 64;
  const int rowb = bm * 128 + wm * 64;
#pragma unroll
  for (int r = 0; r < 4; ++r) {
#pragma unroll
    for (int c = 0; c < 4; ++c) {
      int col = colbase + c * 16 + l15;
      int row = rowb + r * 16 + quad * 4;
#pragma unroll
      for (int v = 0; v < 4; ++v) {
        out[(long)(row + v) * S_DIM + col] = acc[r][c][v];
      }
    }
  }
}

// K3: online column softmax stats. Block = 64 cols x 1024-row segment.
// thread (c=tid&63, rg=tid>>6): rows seg*1024 + 4t + rg. One read of P.
__global__ void __launch_bounds__(256) k_colstats(const float* __restrict__ P,
                                                  float* __restrict__ Pm,
                                                  float* __restrict__ Ps) {
  const int c = threadIdx.x & 63;
  const int rg = threadIdx.x >> 6;
  const int j = blockIdx.x * 64 + c;
  const int seg = blockIdx.y;
  float m = -3.0e38f, s = 0.f;
  for (int t = 0; t < 256; ++t) {
    int i = seg * 1024 + t * 4 + rg;
    float x = P[(long)i * S_DIM + j];
    float mn = fmaxf(m, x);
    s = s * __expf(m - mn) + __expf(x - mn);
    m = mn;
  }
  __shared__ float sm[4][64];
  __shared__ float ss[4][64];
  sm[rg][c] = m;
  ss[rg][c] = s;
  __syncthreads();
  if (threadIdx.x < 64) {
    float mm = sm[0][c];
#pragma unroll
    for (int r = 1; r < 4; ++r) mm = fmaxf(mm, sm[r][c]);
    float sum = 0.f;
#pragma unroll
    for (int r = 0; r < 4; ++r) sum += ss[r][c] * __expf(sm[r][c] - mm);
    Pm[seg * S_DIM + j] = mm;
    Ps[seg * S_DIM + j] = sum;
  }
}

// K3b: combine 8 segment partials per column -> Mcol, 1/Scol
__global__ void __launch_bounds__(256) k_combine(const float* __restrict__ Pm,
                                                 const float* __restrict__ Ps,
                                                 float* __restrict__ Mcol,
                                                 float* __restrict__ Rcol) {
  int j = blockIdx.x * 256 + threadIdx.x;
  float m = Pm[j];
#pragma unroll
  for (int r = 1; r < 8; ++r) m = fmaxf(m, Pm[r * S_DIM + j]);
  float s = 0.f;
#pragma unroll
  for (int r = 0; r < 8; ++r) s += Ps[r * S_DIM + j] * __expf(Pm[r * S_DIM + j] - m);
  Mcol[j] = m;
  Rcol[j] = 1.0f / s;
}

// K4: normalize in place: P[i][j] = exp(P - Mcol[j]) * Rcol[j]
__global__ void __launch_bounds__(256) k_norm(float* __restrict__ P,
                                              const float* __restrict__ Mcol,
                                              const float* __restrict__ Rcol) {
  long gid = (long)blockIdx.x * 256 + threadIdx.x;  // over 16,777,216 float4
  int j4 = (int)(gid & 2047);
  f32x4 x = ((const f32x4*)P)[gid];
  f32x4 a = ((const f32x4*)Mcol)[j4];
  f32x4 r = ((const f32x4*)Rcol)[j4];
  f32x4 o;
#pragma unroll
  for (int e = 0; e < 4; ++e) o[e] = __expf(x[e] - a[e]) * r[e];
  ((f32x4*)P)[gid] = o;
}

// K5: context = enc (col_sum of softmax over the summed axis == 1)
__global__ void __launch_bounds__(256) k_copy(const f32x4* __restrict__ src,
                                              f32x4* __restrict__ dst) {
  long g = (long)blockIdx.x * 256 + threadIdx.x;
  dst[g] = src[g];
}

extern "C" void kernel_launch(void* const* d_in, const int* in_sizes, int n_in,
                              void* d_out, int out_size, void* d_ws, size_t ws_size,
                              hipStream_t stream) {
  const float* enc = (const float*)d_in[0];
  const float* w1 = (const float*)d_in[1];
  const float* w2 = (const float*)d_in[2];

  float* out = (float*)d_out;
  float* ctx = out;                      // [8192][1024] f32  (written last)
  float* attn = out + 8388608;           // [8192][8192] f32

  // Scratch placement (no big ws dependence):
  //  - Qh/Kh fp16 live in the context region (exactly 33,554,432 B) until K5.
  //  - enc_h/w_h fp16 live at the start of the attn region; dead before K2
  //    writes scores over them.
  //  - ws holds only softmax stats (~0.6 MB).
  half_t* Qh = (half_t*)ctx;                                   // 8192x1024 fp16
  half_t* Kh = Qh + 8388608;                                   // 8192x1024 fp16
  half_t* enc_h = (half_t*)attn;                               // 8192x1024 fp16
  half_t* w_h = (half_t*)((char*)attn + 16777216);             // 2048x1024 fp16

  char* ws = (char*)d_ws;
  float* Pm = (float*)ws;                        // [8][8192]
  float* Ps = (float*)(ws + 262144);             // [8][8192]
  float* Mcol = (float*)(ws + 524288);           // [8192]
  float* Rcol = (float*)(ws + 557056);           // [8192]

  // f32 -> fp16 conversions
  k_cvt<<<8192, 256, 0, stream>>>(enc, enc_h);           // 8,388,608 elems
  k_cvt<<<1024, 256, 0, stream>>>(w1, w_h);              // 1,048,576 elems
  k_cvt<<<1024, 256, 0, stream>>>(w2, w_h + 1048576);    // 1,048,576 elems

  // q/k projection (+tanh on q)
  k_gemm_qk<<<dim3(16, 64), 256, 0, stream>>>(enc_h, w_h, Qh, Kh);

  // scores = q @ k^T (f32 into attn region)
  k_gemm_scores<<<dim3(64, 64), 256, 0, stream>>>(Qh, Kh, attn);

  // column softmax: online stats -> combine -> normalize in place
  k_colstats<<<dim3(128, 8), 256, 0, stream>>>(attn, Pm, Ps);
  k_combine<<<32, 256, 0, stream>>>(Pm, Ps, Mcol, Rcol);
  k_norm<<<65536, 256, 0, stream>>>(attn, Mcol, Rcol);

  // context = enc
  k_copy<<<8192, 256, 0, stream>>>((const f32x4*)enc, (f32x4*)ctx);
}

// Round 3
// 768.256 us; speedup vs baseline: 1.0023x; 1.0023x over previous
//
#include <hip/hip_runtime.h>
#include <hip/hip_bf16.h>
#include <math.h>

// Problem: B=1, S=8192, H=1024.
//   q = tanh(enc @ w1^T); k = enc @ w2^T; scores = q @ k^T  [S,S]
//   attn = softmax over rows (axis i) per column j; context = enc (col_sum==1)
// d_out: [0:8388608) context f32, [8388608:) attn f32.

typedef _Float16 half_t;
typedef _Float16 half8 __attribute__((ext_vector_type(8)));
typedef _Float16 half4 __attribute__((ext_vector_type(4)));
typedef float f32x4 __attribute__((ext_vector_type(4)));

#define S_DIM 8192
#define H_DIM 1024

__device__ __forceinline__ void gload16(const void* g, void* l) {
  __builtin_amdgcn_global_load_lds(
      (const __attribute__((address_space(1))) void*)g,
      (__attribute__((address_space(3))) void*)l, 16, 0, 0);
}

// ---------------- f32 -> fp16 convert ----------------------------------------
__global__ void __launch_bounds__(256) k_cvt(const float* __restrict__ src,
                                             half_t* __restrict__ dst) {
  long g = (long)blockIdx.x * 256 + threadIdx.x;
  f32x4 x = ((const f32x4*)src)[g];
  half4 h;
#pragma unroll
  for (int e = 0; e < 4; ++e) h[e] = (half_t)x[e];
  ((half4*)dst)[g] = h;
}

// ---------------- GEMM_BT mainloop (bm/bn must be defined before) -------------
// C[128x128] per block, 4 waves each 64x64, BK=64.
// LDS unit-major [u(0..7)][m(0..127)][8 halfs]; staged with global_load_lds.
#define GEMM_MAINLOOP(APTR, BPTR)                                              \
  __shared__ half_t As[8192];                                                  \
  __shared__ half_t Bs[8192];                                                  \
  const int tid = threadIdx.x;                                                 \
  const int lane = tid & 63;                                                   \
  const int quad = lane >> 4;                                                  \
  const int l15 = lane & 15;                                                   \
  const int wave = tid >> 6;                                                   \
  const int wm = wave & 1;                                                     \
  const int wn = wave >> 1;                                                    \
  int aoff[4], boff[4], loff[4];                                               \
  _Pragma("unroll") for (int t = 0; t < 4; ++t) {                              \
    int f8 = t * 256 + tid;                                                    \
    int u = f8 >> 7;                                                           \
    int m = f8 & 127;                                                          \
    aoff[t] = (bm * 128 + m) * H_DIM + u * 8;                                  \
    boff[t] = (bn * 128 + m) * H_DIM + u * 8;                                  \
    loff[t] = f8 * 8;                                                          \
  }                                                                            \
  f32x4 acc[4][4];                                                             \
  _Pragma("unroll") for (int r = 0; r < 4; ++r)                                \
      _Pragma("unroll") for (int c = 0; c < 4; ++c)                            \
          acc[r][c] = (f32x4){0.f, 0.f, 0.f, 0.f};                             \
  for (int k0 = 0; k0 < H_DIM; k0 += 64) {                                     \
    _Pragma("unroll") for (int t = 0; t < 4; ++t)                              \
        gload16(APTR + aoff[t] + k0, &As[loff[t]]);                            \
    _Pragma("unroll") for (int t = 0; t < 4; ++t)                              \
        gload16(BPTR + boff[t] + k0, &Bs[loff[t]]);                            \
    __syncthreads();                                                           \
    _Pragma("unroll") for (int ki = 0; ki < 2; ++ki) {                         \
      const int u = ki * 4 + quad;                                             \
      half8 af[4], bf[4];                                                      \
      _Pragma("unroll") for (int r = 0; r < 4; ++r)                            \
          af[r] = *(const half8*)&As[(u * 128 + wm * 64 + r * 16 + l15) * 8];  \
      _Pragma("unroll") for (int c = 0; c < 4; ++c)                            \
          bf[c] = *(const half8*)&Bs[(u * 128 + wn * 64 + c * 16 + l15) * 8];  \
      _Pragma("unroll") for (int r = 0; r < 4; ++r)                            \
          _Pragma("unroll") for (int c = 0; c < 4; ++c)                        \
              acc[r][c] = __builtin_amdgcn_mfma_f32_16x16x32_f16(              \
                  af[r], bf[c], acc[r][c], 0, 0, 0);                           \
    }                                                                          \
    __syncthreads();                                                           \
  }

// K1: X[8192,2048] = enc_h @ w_h^T; cols<1024 -> tanh -> Qh, else -> Kh (fp16)
__global__ void __launch_bounds__(256) k_gemm_qk(const half_t* __restrict__ A,
                                                 const half_t* __restrict__ B,
                                                 half_t* __restrict__ Qh,
                                                 half_t* __restrict__ Kh) {
  const int bm = blockIdx.y;
  const int bn = blockIdx.x;
  GEMM_MAINLOOP(A, B)
  const int colbase = bn * 128 + wn * 64;
  const int rowb = bm * 128 + wm * 64;
#pragma unroll
  for (int r = 0; r < 4; ++r) {
#pragma unroll
    for (int c = 0; c < 4; ++c) {
      int col = colbase + c * 16 + l15;
      int row = rowb + r * 16 + quad * 4;
#pragma unroll
      for (int v = 0; v < 4; ++v) {
        float x = acc[r][c][v];
        if (col < 1024) {
          Qh[(long)(row + v) * 1024 + col] = (half_t)tanhf(x);
        } else {
          Kh[(long)(row + v) * 1024 + (col - 1024)] = (half_t)x;
        }
      }
    }
  }
}

// K2: scores[8192,8192] = Qh @ Kh^T, f32 out; fused per-block column softmax
// partials (max, expsum over the block's 128 rows) -> Pm/Ps[64][8192].
// 1D grid 4096, 8x8 supertile swizzle for L2 locality.
template <bool FUSE_STATS>
__global__ void __launch_bounds__(256) k_gemm_scores(const half_t* __restrict__ A,
                                                     const half_t* __restrict__ B,
                                                     float* __restrict__ out,
                                                     float* __restrict__ Pm,
                                                     float* __restrict__ Ps) {
  const int lin = blockIdx.x;
  const int patch = lin >> 6;   // 8x8 patches of 8x8 blocks
  const int local = lin & 63;
  const int bm = (patch >> 3) * 8 + (local >> 3);
  const int bn = (patch & 7) * 8 + (local & 7);
  GEMM_MAINLOOP(A, B)
  const int colbase = bn * 128 + wn * 64;
  const int rowb = bm * 128 + wm * 64;
  // raw score stores (64 dwords/thread)
#pragma unroll
  for (int r = 0; r < 4; ++r) {
#pragma unroll
    for (int c = 0; c < 4; ++c) {
      int col = colbase + c * 16 + l15;
      int row = rowb + r * 16 + quad * 4;
#pragma unroll
      for (int v = 0; v < 4; ++v) {
        out[(long)(row + v) * S_DIM + col] = acc[r][c][v];
      }
    }
  }
  if (FUSE_STATS) {
    // per-column partial over this block's 128 rows
    float cmax[4], csum[4];
#pragma unroll
    for (int c = 0; c < 4; ++c) {
      float m = acc[0][c][0];
#pragma unroll
      for (int r = 0; r < 4; ++r)
#pragma unroll
        for (int v = 0; v < 4; ++v) m = fmaxf(m, acc[r][c][v]);
      // reduce across quad (lanes l15+16*quad share a column)
      m = fmaxf(m, __shfl_xor(m, 16, 64));
      m = fmaxf(m, __shfl_xor(m, 32, 64));
      cmax[c] = m;
      float s = 0.f;
#pragma unroll
      for (int r = 0; r < 4; ++r)
#pragma unroll
        for (int v = 0; v < 4; ++v) s += __expf(acc[r][c][v] - m);
      s += __shfl_xor(s, 16, 64);
      s += __shfl_xor(s, 32, 64);
      csum[c] = s;
    }
    // combine wm=0/1 halves via LDS (reuse As; last mainloop op was barrier)
    float* sred = (float*)As;  // [wm][wn][c][l15][2] = 512 floats
    if (quad == 0) {
#pragma unroll
      for (int c = 0; c < 4; ++c) {
        int idx = ((((wm * 2 + wn) * 4 + c) * 16 + l15) * 2);
        sred[idx] = cmax[c];
        sred[idx + 1] = csum[c];
      }
    }
    __syncthreads();
    if (wm == 0 && quad == 0) {
#pragma unroll
      for (int c = 0; c < 4; ++c) {
        int i0 = ((((0 * 2 + wn) * 4 + c) * 16 + l15) * 2);
        int i1 = ((((1 * 2 + wn) * 4 + c) * 16 + l15) * 2);
        float m0 = sred[i0], s0 = sred[i0 + 1];
        float m1 = sred[i1], s1 = sred[i1 + 1];
        float M = fmaxf(m0, m1);
        float Ssum = s0 * __expf(m0 - M) + s1 * __expf(m1 - M);
        int col = colbase + c * 16 + l15;
        Pm[(long)bm * S_DIM + col] = M;
        Ps[(long)bm * S_DIM + col] = Ssum;
      }
    }
  }
}

// Fallback stats pass (only if ws too small for 64-segment partials)
__global__ void __launch_bounds__(256) k_colstats(const float* __restrict__ P,
                                                  float* __restrict__ Pm,
                                                  float* __restrict__ Ps) {
  const int c = threadIdx.x & 63;
  const int rg = threadIdx.x >> 6;
  const int j = blockIdx.x * 64 + c;
  const int seg = blockIdx.y;
  float m = -3.0e38f, s = 0.f;
  for (int t = 0; t < 256; ++t) {
    int i = seg * 1024 + t * 4 + rg;
    float x = P[(long)i * S_DIM + j];
    float mn = fmaxf(m, x);
    s = s * __expf(m - mn) + __expf(x - mn);
    m = mn;
  }
  __shared__ float sm[4][64];
  __shared__ float ss[4][64];
  sm[rg][c] = m;
  ss[rg][c] = s;
  __syncthreads();
  if (threadIdx.x < 64) {
    float mm = sm[0][c];
#pragma unroll
    for (int r = 1; r < 4; ++r) mm = fmaxf(mm, sm[r][c]);
    float sum = 0.f;
#pragma unroll
    for (int r = 0; r < 4; ++r) sum += ss[r][c] * __expf(sm[r][c] - mm);
    Pm[seg * S_DIM + j] = mm;
    Ps[seg * S_DIM + j] = sum;
  }
}

// combine NSEG segment partials per column -> Mcol, 1/Scol
__global__ void __launch_bounds__(256) k_combine(const float* __restrict__ Pm,
                                                 const float* __restrict__ Ps,
                                                 float* __restrict__ Mcol,
                                                 float* __restrict__ Rcol,
                                                 int nseg) {
  int j = blockIdx.x * 256 + threadIdx.x;
  float m = Pm[j];
  for (int r = 1; r < nseg; ++r) m = fmaxf(m, Pm[(long)r * S_DIM + j]);
  float s = 0.f;
  for (int r = 0; r < nseg; ++r)
    s += Ps[(long)r * S_DIM + j] * __expf(Pm[(long)r * S_DIM + j] - m);
  Mcol[j] = m;
  Rcol[j] = 1.0f / s;
}

// normalize in place + fused context copy.
// Blocks [0,65536): normalize 16,777,216 float4 of attn.
// Blocks [65536, 65536+8192): copy 2,097,152 float4 enc -> ctx.
__global__ void __launch_bounds__(256) k_norm(float* __restrict__ P,
                                              const float* __restrict__ Mcol,
                                              const float* __restrict__ Rcol,
                                              const f32x4* __restrict__ enc,
                                              f32x4* __restrict__ ctx) {
  long b = blockIdx.x;
  if (b >= 65536) {
    long g = (b - 65536) * 256 + threadIdx.x;  // [0, 2,097,152)
    ctx[g] = enc[g];
    return;
  }
  long gid = b * 256 + threadIdx.x;  // over 16,777,216 float4
  int j4 = (int)(gid & 2047);
  f32x4 x = ((const f32x4*)P)[gid];
  f32x4 a = ((const f32x4*)Mcol)[j4];
  f32x4 r = ((const f32x4*)Rcol)[j4];
  f32x4 o;
#pragma unroll
  for (int e = 0; e < 4; ++e) o[e] = __expf(x[e] - a[e]) * r[e];
  ((f32x4*)P)[gid] = o;
}

extern "C" void kernel_launch(void* const* d_in, const int* in_sizes, int n_in,
                              void* d_out, int out_size, void* d_ws, size_t ws_size,
                              hipStream_t stream) {
  const float* enc = (const float*)d_in[0];
  const float* w1 = (const float*)d_in[1];
  const float* w2 = (const float*)d_in[2];

  float* out = (float*)d_out;
  float* ctx = out;                      // [8192][1024] f32 (written last)
  float* attn = out + 8388608;           // [8192][8192] f32

  // Scratch placement:
  //  - Qh/Kh fp16 live in the context region (exactly 33,554,432 B) until norm.
  //  - enc_h/w_h fp16 live at the start of the attn region; dead before K2.
  //  - ws: softmax partials. Fused path needs 64-seg partials (4.25 MB).
  half_t* Qh = (half_t*)ctx;                                   // 8192x1024 fp16
  half_t* Kh = Qh + 8388608;                                   // 8192x1024 fp16
  half_t* enc_h = (half_t*)attn;                               // 8192x1024 fp16
  half_t* w_h = (half_t*)((char*)attn + 16777216);             // 2048x1024 fp16

  const bool fuse = ws_size >= (size_t)(64 + 64 + 2) * S_DIM * 4;
  const int nseg = fuse ? 64 : 8;
  char* ws = (char*)d_ws;
  float* Pm = (float*)ws;                                  // [nseg][8192]
  float* Ps = (float*)(ws + (size_t)nseg * S_DIM * 4);     // [nseg][8192]
  float* Mcol = (float*)(ws + (size_t)2 * nseg * S_DIM * 4);
  float* Rcol = Mcol + S_DIM;

  // f32 -> fp16 conversions
  k_cvt<<<8192, 256, 0, stream>>>(enc, enc_h);
  k_cvt<<<1024, 256, 0, stream>>>(w1, w_h);
  k_cvt<<<1024, 256, 0, stream>>>(w2, w_h + 1048576);

  // q/k projection (+tanh on q)
  k_gemm_qk<<<dim3(16, 64), 256, 0, stream>>>(enc_h, w_h, Qh, Kh);

  // scores = q @ k^T (f32 into attn region), with fused column stats
  if (fuse) {
    k_gemm_scores<true><<<4096, 256, 0, stream>>>(Qh, Kh, attn, Pm, Ps);
  } else {
    k_gemm_scores<false><<<4096, 256, 0, stream>>>(Qh, Kh, attn, Pm, Ps);
    k_colstats<<<dim3(128, 8), 256, 0, stream>>>(attn, Pm, Ps);
  }
  k_combine<<<32, 256, 0, stream>>>(Pm, Ps, Mcol, Rcol, nseg);

  // normalize in place + context copy fused (65536 norm blocks + 8192 copy)
  k_norm<<<73728, 256, 0, stream>>>(attn, Mcol, Rcol, (const f32x4*)enc,
                                    (f32x4*)ctx);
}